// Round 1
// baseline (57.070 us; speedup 1.0000x reference)
//
#include <hip/hip_runtime.h>
#include <hip/hip_bf16.h>

// VQ-VAE vector quantizer, MI355X.
// Pipeline: [k_trans] lat[B,D,H,W]->flatA[N,D] bf16  |  [k_prep] emb->bf16 + ||e||^2
//           [k_argmin] scores = ||e||^2 - 2*A.E^T via mfma_16x16x32_bf16, per-row argmin
//           [k_gather] q = emb[idx] (fp32) + per-block loss partials
//           [k_final]  vq_loss = 1.25 * sum/ (N*D)

#define NPOS 32768
#define DIM  128
#define KCB  1024

typedef __attribute__((ext_vector_type(8))) short bf16x8;
typedef __attribute__((ext_vector_type(4))) float f32x4;

// workspace layout (bytes)
#define WS_A 0u            // bf16 [32768][128]  = 8388608
#define WS_E 8388608u      // bf16 [1024][128]   = 262144
#define WS_C 8650752u      // f32  [1024]        = 4096
#define WS_I 8654848u      // i32  [32768]       = 131072
#define WS_P 8785920u      // f32  [4096]        = 16384

// ---------------- transpose latents [B,D,HW] -> flatA[N=B*HW][D] bf16 ----------------
__global__ __launch_bounds__(256) void k_trans(const float* __restrict__ lat,
                                               __hip_bfloat16* __restrict__ A) {
    __shared__ float t[32][33];
    int blk = blockIdx.x;
    int b = blk >> 7, rest = blk & 127;
    int d0 = (rest >> 5) << 5;      // 4 d-tiles
    int hw0 = (rest & 31) << 5;     // 32 hw-tiles
    int tx = threadIdx.x & 31, ty = threadIdx.x >> 5;
#pragma unroll
    for (int i = 0; i < 4; ++i) {
        int d = d0 + ty + i * 8;
        t[ty + i * 8][tx] = lat[((size_t)(b * 128 + d) << 10) + hw0 + tx];
    }
    __syncthreads();
#pragma unroll
    for (int i = 0; i < 4; ++i) {
        int hwl = ty + i * 8;
        int n = (b << 10) + hw0 + hwl;
        A[((size_t)n << 7) + d0 + tx] = __float2bfloat16(t[tx][hwl]);
    }
}

// ---------------- codebook prep: bf16 copy + squared norms ----------------
__global__ __launch_bounds__(128) void k_prep(const float* __restrict__ emb,
                                              __hip_bfloat16* __restrict__ E,
                                              float* __restrict__ cn) {
    int k = blockIdx.x, d = threadIdx.x;
    float v = emb[(k << 7) + d];
    E[(k << 7) + d] = __float2bfloat16(v);
    float s = v * v;
#pragma unroll
    for (int m = 1; m < 64; m <<= 1) s += __shfl_xor(s, m);
    __shared__ float sh[2];
    if ((threadIdx.x & 63) == 0) sh[threadIdx.x >> 6] = s;
    __syncthreads();
    if (threadIdx.x == 0) cn[k] = sh[0] + sh[1];
}

// ---------------- main: per-row argmin over 1024 codes via MFMA ----------------
// block = 256 thr (4 waves), tile = 64 rows x 128 codes/ct x 8 col-tiles, Kdim=128.
// LDS XOR-swizzle (byte ^= (row&7)<<4) on both staging write and fragment read (G4).
__global__ __launch_bounds__(256) void k_argmin(const __hip_bfloat16* __restrict__ A,
                                                const __hip_bfloat16* __restrict__ E,
                                                const float* __restrict__ cn,
                                                int* __restrict__ idxout) {
    __shared__ char lds[49152];
    char* ldsA = lds;           // 64 rows * 256 B
    char* ldsE = lds + 16384;   // 128 rows * 256 B
    const int tid = threadIdx.x;
    const int bm = blockIdx.x;                 // 512 blocks of 64 rows
    const int lane = tid & 63, wid = tid >> 6; // wave covers cols [wid*32, +32)
    const int l15 = lane & 15, lg = lane >> 4;

    // stage A rows [bm*64, +64) once
    {
        const uint4* Ag = (const uint4*)(A + ((size_t)bm << 13));
#pragma unroll
        for (int i = 0; i < 4; ++i) {
            int chunk = tid + i * 256;                 // 1024 chunks of 16B
            int row = chunk >> 4, c16 = chunk & 15;
            uint4 v = Ag[chunk];
            *(uint4*)(ldsA + row * 256 + ((c16 * 16) ^ ((row & 7) << 4))) = v;
        }
    }

    float run_s[4][4]; int run_i[4][4];
#pragma unroll
    for (int m = 0; m < 4; ++m)
#pragma unroll
        for (int r = 0; r < 4; ++r) { run_s[m][r] = 3.0e38f; run_i[m][r] = 0; }

    for (int ct = 0; ct < 8; ++ct) {
        // stage E tile [ct*128, +128) rows
        const uint4* Eg = (const uint4*)(E + ((size_t)ct << 14));
#pragma unroll
        for (int i = 0; i < 8; ++i) {
            int chunk = tid + i * 256;                 // 2048 chunks
            int row = chunk >> 4, c16 = chunk & 15;
            uint4 v = Eg[chunk];
            *(uint4*)(ldsE + row * 256 + ((c16 * 16) ^ ((row & 7) << 4))) = v;
        }
        __syncthreads();

        f32x4 acc[4][2];
#pragma unroll
        for (int m = 0; m < 4; ++m)
#pragma unroll
            for (int c = 0; c < 2; ++c) acc[m][c] = (f32x4){0.f, 0.f, 0.f, 0.f};

#pragma unroll
        for (int ds = 0; ds < 4; ++ds) {
            int cb = ds * 64 + lg * 16;                // byte col in 256B row
            bf16x8 af[4], bfr[2];
#pragma unroll
            for (int m = 0; m < 4; ++m) {
                int r = m * 16 + l15;
                af[m] = *(const bf16x8*)(ldsA + r * 256 + (cb ^ ((r & 7) << 4)));
            }
#pragma unroll
            for (int c = 0; c < 2; ++c) {
                int r = wid * 32 + c * 16 + l15;
                bfr[c] = *(const bf16x8*)(ldsE + r * 256 + (cb ^ ((r & 7) << 4)));
            }
#pragma unroll
            for (int m = 0; m < 4; ++m)
#pragma unroll
                for (int c = 0; c < 2; ++c)
                    acc[m][c] = __builtin_amdgcn_mfma_f32_16x16x32_bf16(af[m], bfr[c], acc[m][c], 0, 0, 0);
        }

        // per-lane running argmin update (k ascending over (ct,c) -> strict < keeps lowest idx)
#pragma unroll
        for (int c = 0; c < 2; ++c) {
            int kg = ct * 128 + wid * 32 + c * 16 + l15;
            float cv = cn[kg];
#pragma unroll
            for (int m = 0; m < 4; ++m)
#pragma unroll
                for (int r = 0; r < 4; ++r) {
                    float s = fmaf(-2.0f, acc[m][c][r], cv);
                    if (s < run_s[m][r]) { run_s[m][r] = s; run_i[m][r] = kg; }
                }
        }
        __syncthreads();
    }

    // butterfly across the 16 lanes holding one C-row (col = lane&15)
#pragma unroll
    for (int m = 0; m < 4; ++m)
#pragma unroll
        for (int r = 0; r < 4; ++r) {
            float s = run_s[m][r]; int bi = run_i[m][r];
#pragma unroll
            for (int mask = 1; mask < 16; mask <<= 1) {
                float os = __shfl_xor(s, mask);
                int   oi = __shfl_xor(bi, mask);
                if (os < s || (os == s && oi < bi)) { s = os; bi = oi; }
            }
            run_s[m][r] = s; run_i[m][r] = bi;
        }
    if (l15 == 0) {
#pragma unroll
        for (int m = 0; m < 4; ++m)
#pragma unroll
            for (int r = 0; r < 4; ++r) {
                int row = (bm << 6) + m * 16 + lg * 4 + r;   // C row = (lane>>4)*4+reg
                idxout[row] = run_i[m][r];
            }
    }
}

// ---------------- gather + loss partials ----------------
__global__ __launch_bounds__(256) void k_gather(const float* __restrict__ lat,
                                                const float* __restrict__ emb,
                                                const int* __restrict__ idx,
                                                float* __restrict__ outq,
                                                float* __restrict__ partial) {
    int g = blockIdx.x * 256 + threadIdx.x;   // 1M threads, float4 each
    int o4 = g << 2;
    int hw = o4 & 1023;
    int d  = (o4 >> 10) & 127;
    int b  = o4 >> 17;
    int nb = (b << 10) + hw;
    const float4 lv = *(const float4*)(lat + o4);
    int i0 = idx[nb], i1 = idx[nb + 1], i2 = idx[nb + 2], i3 = idx[nb + 3];
    float q0 = emb[((size_t)i0 << 7) + d];
    float q1 = emb[((size_t)i1 << 7) + d];
    float q2 = emb[((size_t)i2 << 7) + d];
    float q3 = emb[((size_t)i3 << 7) + d];
    float4 qv = {q0, q1, q2, q3};
    *(float4*)(outq + o4) = qv;
    float e0 = q0 - lv.x, e1 = q1 - lv.y, e2 = q2 - lv.z, e3 = q3 - lv.w;
    float ls = e0 * e0 + e1 * e1 + e2 * e2 + e3 * e3;
#pragma unroll
    for (int m = 1; m < 64; m <<= 1) ls += __shfl_xor(ls, m);
    __shared__ float sh[4];
    if ((threadIdx.x & 63) == 0) sh[threadIdx.x >> 6] = ls;
    __syncthreads();
    if (threadIdx.x == 0) partial[blockIdx.x] = sh[0] + sh[1] + sh[2] + sh[3];
}

__global__ __launch_bounds__(256) void k_final(const float* __restrict__ partial,
                                               float* __restrict__ loss) {
    float s = 0.f;
    for (int i = threadIdx.x; i < 4096; i += 256) s += partial[i];
#pragma unroll
    for (int m = 1; m < 64; m <<= 1) s += __shfl_xor(s, m);
    __shared__ float sh[4];
    if ((threadIdx.x & 63) == 0) sh[threadIdx.x >> 6] = s;
    __syncthreads();
    if (threadIdx.x == 0) loss[0] = (sh[0] + sh[1] + sh[2] + sh[3]) * (1.25f / 4194304.0f);
}

extern "C" void kernel_launch(void* const* d_in, const int* in_sizes, int n_in,
                              void* d_out, int out_size, void* d_ws, size_t ws_size,
                              hipStream_t stream) {
    const float* lat = (const float*)d_in[0];   // [32,128,32,32]
    const float* emb = (const float*)d_in[1];   // [1024,128]
    float* out = (float*)d_out;                 // q (4194304) + vq_loss (1)
    char* ws = (char*)d_ws;
    __hip_bfloat16* A = (__hip_bfloat16*)(ws + WS_A);
    __hip_bfloat16* E = (__hip_bfloat16*)(ws + WS_E);
    float* cn  = (float*)(ws + WS_C);
    int*   idx = (int*)(ws + WS_I);
    float* prt = (float*)(ws + WS_P);

    k_trans <<<4096, 256, 0, stream>>>(lat, A);
    k_prep  <<<1024, 128, 0, stream>>>(emb, E, cn);
    k_argmin<<<512,  256, 0, stream>>>(A, E, cn, idx);
    k_gather<<<4096, 256, 0, stream>>>(lat, emb, idx, out, prt);
    k_final <<<1,    256, 0, stream>>>(prt, out + 4194304);
}